// Round 10
// baseline (348.815 us; speedup 1.0000x reference)
//
#include <hip/hip_runtime.h>

// AutoCorrelation attention (Autoformer) for B=16, L=2048, d=512, top_k=7.
// R1: XOR-swizzled GEMM LDS (conflict-free MFMA staging).
// R2: FFT rewrite — fused double radix-2 LDS passes + register tail.
// R3: 16x16x32 f16 MFMA + XCD-aware tile decode.
// R4: plain-f16 Q/K path, f16 Qt/Kt.
// R5: merged QK GEMM (stacked weights, SPLITB); reduce_sp split.
// R6: (f32-direct staging — REVERTED.)  R7: all-f16 GEMMs + fused cvt.
// R8: (depth-1 dbuf — NEUTRAL: __syncthreads drains vmcnt(0), m97 ceiling.)
// R9: T3+T4 counted-vmcnt pipeline: 8 waves, 3-buffer LDS (144 KB), depth-2
//     prefetch, raw s_barrier + "s_waitcnt vmcnt(6)" (never 0 in main loop).

typedef _Float16 f16;
typedef _Float16 f16x8 __attribute__((ext_vector_type(8)));
typedef _Float16 f16x4 __attribute__((ext_vector_type(4)));
typedef float    f32x4 __attribute__((ext_vector_type(4)));

#define PSI(i) ((i) + ((i) >> 3))          // z anti-conflict pad (2048 -> 2304)
#define TWI(j) ((j) + ((j) >> 4))          // tw anti-conflict pad (1024 -> 1088)

__device__ __forceinline__ float2 f2add(float2 a, float2 b) { return make_float2(a.x + b.x, a.y + b.y); }
__device__ __forceinline__ float2 f2sub(float2 a, float2 b) { return make_float2(a.x - b.x, a.y - b.y); }
__device__ __forceinline__ float2 cmul(float2 a, float2 b)  { return make_float2(a.x * b.x - a.y * b.y, a.x * b.y + a.y * b.x); }

// ---------------- conversions: f32 -> f16 -----------------------------------
__global__ __launch_bounds__(256) void cvt_inputs(
    const float* __restrict__ q, const float* __restrict__ k, const float* __restrict__ v,
    f16* __restrict__ xq, f16* __restrict__ xk, f16* __restrict__ xv)
{
    const float* src = (blockIdx.y == 0) ? q : (blockIdx.y == 1) ? k : v;
    f16*         dst = (blockIdx.y == 0) ? xq : (blockIdx.y == 1) ? xk : xv;
    const int i = blockIdx.x * 256 + threadIdx.x;
    float4 val = ((const float4*)src)[i];
    f16x4 h = { (f16)val.x, (f16)val.y, (f16)val.z, (f16)val.w };
    ((f16x4*)dst)[i] = h;
}

__global__ __launch_bounds__(256) void cvt_weights(
    const float* __restrict__ w0, const float* __restrict__ w1,
    const float* __restrict__ w2, const float* __restrict__ w3,
    f16* __restrict__ o0, f16* __restrict__ o1, f16* __restrict__ o2, f16* __restrict__ o3)
{
    const float* src = (blockIdx.y == 0) ? w0 : (blockIdx.y == 1) ? w1 : (blockIdx.y == 2) ? w2 : w3;
    f16*         dst = (blockIdx.y == 0) ? o0 : (blockIdx.y == 1) ? o1 : (blockIdx.y == 2) ? o2 : o3;
    const int i = blockIdx.x * 256 + threadIdx.x;
    float4 val = ((const float4*)src)[i];
    f16x4 h = { (f16)val.x, (f16)val.y, (f16)val.z, (f16)val.w };
    ((f16x4*)dst)[i] = h;
}

// ---------------- GEMM staging: one 64-col K-slab of an NR*64-row operand ---
// 512 threads; NR loads/thread; LDS linear (lane-contiguous 16B), global
// source octet pre-swizzled by (row&7) — read side applies the same XOR.
template<int NR>
__device__ __forceinline__ void stage_op(const f16* __restrict__ G, int row0, int k0,
                                         f16* __restrict__ lds, int tid)
{
#pragma unroll
    for (int q = 0; q < NR; ++q) {
        const int r = q * 64 + (tid >> 3);
        const int u = (tid & 7) ^ ((tid >> 3) & 7);
        const f16* g = G + (size_t)(row0 + r) * 512 + k0 + u * 8;
        f16* d = lds + q * 4096 + (tid >> 6) * 512;     // wave-uniform base
        __builtin_amdgcn_global_load_lds(
            (const __attribute__((address_space(1))) void*)g,
            (__attribute__((address_space(3))) void*)d, 16, 0, 0);
    }
}

// ---------------- NT GEMM: C[M,N] = A * B^T (+bias), f16 16x16x32 MFMA ------
// 8 waves; per-wave 64x64 output; BM = WM*64, BN = WN*64, BK = 64, K = 512.
// 3-buffer LDS, depth-2 prefetch, counted vmcnt(6) + raw s_barrier (T3+T4).
// SWZ=1 groups same-nt blocks on one XCD, SWZ=2 same-mt. SPLITB: B/bias
// switch at mt >= 2^(MT_L2-1).
template<int F16OUT, int WM_L2, int MT_L2, int NT_L2, int SWZ, int SPLITB>
__global__ __launch_bounds__(512, 2) void gemm_nt(
    const f16* __restrict__ A0, const f16* __restrict__ B0, const f16* __restrict__ B1,
    void* __restrict__ Cout, int N,
    const float* __restrict__ bias_q, const float* __restrict__ bias_k,
    const float* __restrict__ bias_col)
{
    constexpr int WM = 1 << WM_L2;   // waves along M
    constexpr int WN = 8 >> WM_L2;   // waves along N
    constexpr int BM = WM * 64;
    constexpr int BN = WN * 64;
    constexpr int NKT = 8;           // K=512 / BK=64

    __shared__ f16 As[3][BM * 64];
    __shared__ f16 Bs[3][BN * 64];

    const int tid  = threadIdx.x;
    const int wave = tid >> 6, lane = tid & 63;

    int mt, nt;
    if (SWZ == 1) {
        const int xcd = blockIdx.x & 7, slot = blockIdx.x >> 3;
        mt = slot & ((1 << MT_L2) - 1);
        nt = (xcd << (NT_L2 - 3)) | (slot >> MT_L2);
    } else if (SWZ == 2) {
        const int xcd = blockIdx.x & 7, slot = blockIdx.x >> 3;
        nt = slot & ((1 << NT_L2) - 1);
        mt = (xcd << (MT_L2 - 3)) | (slot >> NT_L2);
    } else {
        nt = blockIdx.x & ((1 << NT_L2) - 1);
        mt = blockIdx.x >> NT_L2;
    }
    const int m0 = mt * BM, n0 = nt * BN;

    const bool useB1 = SPLITB && (mt >= (1 << (MT_L2 - 1)));
    const f16* Bg = useB1 ? B1 : B0;
    const float* brow = SPLITB
        ? (useB1 ? bias_k - (1 << (MT_L2 - 1)) * BM : bias_q)
        : bias_q;

    f32x4 acc[4][4];
#pragma unroll
    for (int m = 0; m < 4; ++m)
#pragma unroll
        for (int n = 0; n < 4; ++n) acc[m][n] = (f32x4){0.f, 0.f, 0.f, 0.f};

    const int fr = lane & 15;
    const int kg = (lane >> 4) * 8;          // k-group base within 32-wide K step
    const int rowm = fr & 7;                 // read-side swizzle key
    const int wr = wave >> (3 - WM_L2);      // wave row (0..WM-1)
    const int wc = wave & (WN - 1);          // wave col (0..WN-1)
    const int warow = wr * 64 + fr;
    const int wbrow = wc * 64 + fr;

#define GEMM_COMPUTE(cur_)                                                                          \
    _Pragma("unroll")                                                                               \
    for (int k2 = 0; k2 < 2; ++k2) {                                                                \
        const int kb = k2 * 32 + kg;                                                                \
        const int col = ((kb >> 3) ^ rowm) << 3;                                                    \
        f16x8 af[4], bf[4];                                                                         \
        _Pragma("unroll")                                                                           \
        for (int m = 0; m < 4; ++m) af[m] = *(const f16x8*)&As[cur_][(warow + m * 16) * 64 + col];  \
        _Pragma("unroll")                                                                           \
        for (int n = 0; n < 4; ++n) bf[n] = *(const f16x8*)&Bs[cur_][(wbrow + n * 16) * 64 + col];  \
        _Pragma("unroll")                                                                           \
        for (int m = 0; m < 4; ++m)                                                                 \
            _Pragma("unroll")                                                                       \
            for (int n = 0; n < 4; ++n)                                                             \
                acc[m][n] = __builtin_amdgcn_mfma_f32_16x16x32_f16(af[m], bf[n], acc[m][n], 0, 0, 0); \
    }

    // prologue: tiles 0 and 1 in flight; wait for tile 0 only (vmcnt(6)).
    stage_op<WM>(A0, m0, 0, As[0], tid);
    stage_op<WN>(Bg, n0, 0, Bs[0], tid);
    stage_op<WM>(A0, m0, 64, As[1], tid);
    stage_op<WN>(Bg, n0, 64, Bs[1], tid);
    asm volatile("s_waitcnt vmcnt(6)" ::: "memory");
    __builtin_amdgcn_s_barrier();

#pragma unroll 1
    for (int kk = 0; kk < NKT; ++kk) {
        const int cur = kk % 3;
        if (kk < NKT - 2) {
            const int nxt = (kk + 2) % 3;
            stage_op<WM>(A0, m0, (kk + 2) * 64, As[nxt], tid);
            stage_op<WN>(Bg, n0, (kk + 2) * 64, Bs[nxt], tid);
        }
        GEMM_COMPUTE(cur);
        if (kk < NKT - 2) {
            // STAGE(kk+2) still in flight (6 loads) — wait only for STAGE(kk+1)
            asm volatile("s_waitcnt vmcnt(6) lgkmcnt(0)" ::: "memory");
            __builtin_amdgcn_s_barrier();
        } else if (kk == NKT - 2) {
            asm volatile("s_waitcnt vmcnt(0) lgkmcnt(0)" ::: "memory");
            __builtin_amdgcn_s_barrier();
        }
    }
#undef GEMM_COMPUTE

    const int crow = m0 + wr * 64 + (lane >> 4) * 4;
    const int ccol = n0 + wc * 64 + fr;
#pragma unroll
    for (int m = 0; m < 4; ++m)
#pragma unroll
        for (int n = 0; n < 4; ++n) {
            const int col = ccol + n * 16;
            const float bc = bias_col ? bias_col[col] : 0.f;
#pragma unroll
            for (int j = 0; j < 4; ++j) {
                const int row = crow + m * 16 + j;
                float v = acc[m][n][j] + bc + (brow ? brow[row] : 0.f);
                if (F16OUT) ((f16*)Cout)[(size_t)row * N + col] = (f16)v;
                else        ((float*)Cout)[(size_t)row * N + col] = v;
            }
        }
}

// ---------------- 2048-pt FFT: fused double radix-2 DIF passes --------------
template<int S>
__device__ __forceinline__ void fft_pass2(float2* __restrict__ z, const float2* __restrict__ tw, int tid)
{
    constexpr int m = 1024 >> S;
    constexpr int h = m >> 1;
#pragma unroll
    for (int rep = 0; rep < 2; ++rep) {
        const int idx = tid + rep * 256;
        const int j2  = idx & (h - 1);
        const int blk = idx >> (9 - S);
        const int i   = (blk << (11 - S)) + j2;
        const float2 w1 = tw[TWI(j2 << S)];
        const float2 w2 = tw[TWI(j2 << (S + 1))];
        float2 a = z[PSI(i)], b = z[PSI(i + h)], c = z[PSI(i + m)], d = z[PSI(i + m + h)];
        float2 a1 = f2add(a, c);
        float2 c1 = cmul(f2sub(a, c), w1);
        float2 b1 = f2add(b, d);
        float2 t0 = cmul(f2sub(b, d), w1);
        float2 d1 = make_float2(t0.y, -t0.x);            // * (-i)  (w_{j+h} = -i*w_j)
        z[PSI(i)]         = f2add(a1, b1);
        z[PSI(i + h)]     = cmul(f2sub(a1, b1), w2);
        z[PSI(i + m)]     = f2add(c1, d1);
        z[PSI(i + m + h)] = cmul(f2sub(c1, d1), w2);
    }
    __syncthreads();
}

__device__ __forceinline__ void fft_tail_scatter(float2* __restrict__ z, int tid)
{
    float2 v[8];
    const int p0 = tid * 8;
#pragma unroll
    for (int e = 0; e < 8; ++e) v[e] = z[PSI(p0 + e)];
    __syncthreads();
    constexpr float RS = 0.70710678118654752f;
    const float2 W8[4] = { {1.f, 0.f}, {RS, -RS}, {0.f, -1.f}, {-RS, -RS} };
#pragma unroll
    for (int e = 0; e < 4; ++e) {
        float2 t = f2sub(v[e], v[e + 4]);
        v[e]     = f2add(v[e], v[e + 4]);
        v[e + 4] = cmul(t, W8[e]);
    }
#pragma unroll
    for (int base = 0; base < 8; base += 4) {
        float2 t0 = f2sub(v[base], v[base + 2]);
        v[base]     = f2add(v[base], v[base + 2]);
        v[base + 2] = t0;
        float2 t1 = f2sub(v[base + 1], v[base + 3]);
        v[base + 1] = f2add(v[base + 1], v[base + 3]);
        v[base + 3] = make_float2(t1.y, -t1.x);
    }
#pragma unroll
    for (int base = 0; base < 8; base += 2) {
        float2 t = f2sub(v[base], v[base + 1]);
        v[base]     = f2add(v[base], v[base + 1]);
        v[base + 1] = t;
    }
    const int br8t = (int)(__brev((unsigned)tid) >> 24);
    const int BR3[8] = {0, 4, 2, 6, 1, 5, 3, 7};
#pragma unroll
    for (int e = 0; e < 8; ++e) {
        const int f = br8t + (BR3[e] << 8);
        z[PSI(f)] = v[e];
    }
    __syncthreads();
}

__device__ __forceinline__ void fft2048_natural(float2* __restrict__ z, const float2* __restrict__ tw, int tid)
{
    fft_pass2<0>(z, tw, tid);
    fft_pass2<2>(z, tw, tid);
    fft_pass2<4>(z, tw, tid);
    fft_pass2<6>(z, tw, tid);
    fft_tail_scatter(z, tid);   // z now holds Z[f] at natural f (PSI-mapped)
}

__device__ __forceinline__ void fill_tw(float2* __restrict__ tw, int tid)
{
    for (int j = tid; j < 1024; j += 256) {
        float sv, cv;
        sincospif(-(float)j * (1.0f / 1024.0f), &sv, &cv);   // e^{-2 pi i j / 2048}
        tw[TWI(j)] = make_float2(cv, sv);
    }
}

// 8 channels/block: z = q + i*k packed FFT; S_c = Q*conj(K) accumulated in
// registers over channels; Hermitian half f=0..1024 written to Sp.
__global__ __launch_bounds__(256) void fft_corr(
    const f16* __restrict__ Qt, const f16* __restrict__ Kt,
    float2* __restrict__ Sp)
{
    __shared__ float2 z[2304];
    __shared__ float2 tw[1088];
    const int tid = threadIdx.x;
    const int grp = blockIdx.x;   // 0..63 channel group (8 ch each)
    const int b   = blockIdx.y;   // 0..15 batch

    fill_tw(tw, tid);
    float2 racc[5];
#pragma unroll
    for (int r = 0; r < 5; ++r) racc[r] = make_float2(0.f, 0.f);
    __syncthreads();

    for (int ch = 0; ch < 8; ++ch) {
        const int c = grp * 8 + ch;
        const f16x8* qr = (const f16x8*)(Qt + ((size_t)c * 16 + b) * 2048);
        const f16x8* kr = (const f16x8*)(Kt + ((size_t)c * 16 + b) * 2048);
        f16x8 qv = qr[tid], kv = kr[tid];
        const int e0 = tid * 8;
#pragma unroll
        for (int j = 0; j < 8; ++j)
            z[PSI(e0 + j)] = make_float2((float)qv[j], (float)kv[j]);
        __syncthreads();
        fft2048_natural(z, tw, tid);
#pragma unroll
        for (int r = 0; r < 5; ++r) {
            const int f = tid + (r << 8);
            if (f <= 1024) {
                const int pf = (2048 - f) & 2047;
                float2 Zf  = z[PSI(f)];
                float2 Zc0 = z[PSI(pf)];
                float qx = 0.5f * (Zf.x + Zc0.x), qy = 0.5f * (Zf.y - Zc0.y);
                float dx = Zf.x - Zc0.x,          dy = Zf.y + Zc0.y;
                float kx = 0.5f * dy,             ky = -0.5f * dx;   // K = -i*D/2
                racc[r].x += qx * kx + qy * ky;                      // Q*conj(K)
                racc[r].y += qy * kx - qx * ky;
            }
        }
        __syncthreads();
    }
    float2* out = Sp + ((size_t)b * 64 + grp) * 1025;
#pragma unroll
    for (int r = 0; r < 5; ++r) {
        const int f = tid + (r << 8);
        if (f <= 1024) out[f] = racc[r];
    }
}

// fixed-order sum of the 64 per-group spectra -> Sred[b][f]
__global__ __launch_bounds__(256) void reduce_sp(
    const float2* __restrict__ Sp, float2* __restrict__ Sred)
{
    const int b = blockIdx.x;
    const int f = blockIdx.y * 256 + threadIdx.x;
    if (f > 1024) return;
    const float2* base = Sp + (size_t)b * 64 * 1025 + f;
    float sx = 0.f, sy = 0.f;
#pragma unroll 8
    for (int g = 0; g < 64; ++g) {
        float2 p = base[(size_t)g * 1025];
        sx += p.x; sy += p.y;
    }
    Sred[b * 1025 + f] = make_float2(sx, sy);
}

// rebuild full spectrum from Hermitian half, inverse FFT via conj trick
// (same natural-order forward FFT), write mean_value.
__global__ __launch_bounds__(256) void ifft_mean(
    const float2* __restrict__ Sred, float* __restrict__ mv)
{
    __shared__ float2 z[2304];
    __shared__ float2 tw[1088];
    const int tid = threadIdx.x;
    const int b   = blockIdx.x;
    fill_tw(tw, tid);
#pragma unroll
    for (int r = 0; r < 5; ++r) {
        const int f = tid + (r << 8);
        if (f <= 1024) {
            float2 s = Sred[b * 1025 + f];
            z[PSI(f)] = make_float2(s.x, -s.y);                     // conj(S[f])
            if (f >= 1 && f <= 1023)
                z[PSI(2048 - f)] = make_float2(s.x, s.y);           // conj(S[2048-f]) = S[f]
        }
    }
    __syncthreads();
    fft2048_natural(z, tw, tid);
    const float scale = 1.0f / (2048.0f * 512.0f);  // irfft 1/N and channel mean
    for (int t = tid; t < 2048; t += 256)
        mv[(size_t)b * 2048 + t] = z[PSI(t)].x * scale;
}

// top-7 lags of batch-mean corr + per-batch softmax weights. One block.
__global__ __launch_bounds__(256) void select_topk(
    const float* __restrict__ mv, int* __restrict__ sel, float* __restrict__ wsm)
{
    __shared__ float u[2048];
    __shared__ float rv[256];
    __shared__ int   ri[256];
    __shared__ int   ssel[7];
    const int tid = threadIdx.x;
    for (int t = tid; t < 2048; t += 256) {
        float s = 0.f;
        for (int b = 0; b < 16; ++b) s += mv[b * 2048 + t];
        u[t] = s;
    }
    __syncthreads();
    for (int k = 0; k < 7; ++k) {
        float best = -3.4e38f; int bi = 0x7fffffff;
        for (int t = tid; t < 2048; t += 256)
            if (u[t] > best) { best = u[t]; bi = t; }
        rv[tid] = best; ri[tid] = bi;
        __syncthreads();
        for (int off = 128; off > 0; off >>= 1) {
            if (tid < off) {
                if (rv[tid + off] > rv[tid] ||
                    (rv[tid + off] == rv[tid] && ri[tid + off] < ri[tid])) {
                    rv[tid] = rv[tid + off]; ri[tid] = ri[tid + off];
                }
            }
            __syncthreads();
        }
        if (tid == 0) { ssel[k] = ri[0]; sel[k] = ri[0]; u[ri[0]] = -3.4e38f; }
        __syncthreads();
    }
    if (tid < 16) {
        float vals[7], mx = -3.4e38f;
        for (int k = 0; k < 7; ++k) { vals[k] = mv[tid * 2048 + ssel[k]]; mx = fmaxf(mx, vals[k]); }
        float se = 0.f;
        for (int k = 0; k < 7; ++k) { vals[k] = expf(vals[k] - mx); se += vals[k]; }
        for (int k = 0; k < 7; ++k) wsm[tid * 7 + k] = vals[k] / se;
    }
}

// agg[b,l,c] = sum_k w[b,k] * V[b,(l+sel[k])%L,c]
__global__ __launch_bounds__(256) void aggregate(
    const f16* __restrict__ V, const int* __restrict__ sel,
    const float* __restrict__ wsm, f16* __restrict__ agg)
{
    __shared__ int   sidx[7];
    __shared__ float sw[7];
    const int bl = blockIdx.x;
    const int b = bl >> 11, l = bl & 2047;
    if (threadIdx.x < 7) { sidx[threadIdx.x] = sel[threadIdx.x]; sw[threadIdx.x] = wsm[b * 7 + threadIdx.x]; }
    __syncthreads();
    const int c = threadIdx.x;
    float a0 = 0.f, a1 = 0.f;
#pragma unroll
    for (int k = 0; k < 7; ++k) {
        const int lk = (l + sidx[k]) & 2047;
        const f16* row = V + ((size_t)b * 2048 + lk) * 512;
        a0 += sw[k] * (float)row[c];
        a1 += sw[k] * (float)row[c + 256];
    }
    f16* orow = agg + ((size_t)b * 2048 + l) * 512;
    orow[c]       = (f16)a0;
    orow[c + 256] = (f16)a1;
}

extern "C" void kernel_launch(void* const* d_in, const int* in_sizes, int n_in,
                              void* d_out, int out_size, void* d_ws, size_t ws_size,
                              hipStream_t stream)
{
    (void)in_sizes; (void)n_in; (void)out_size; (void)ws_size;
    const float* queries = (const float*)d_in[0];
    const float* keys    = (const float*)d_in[1];
    const float* values  = (const float*)d_in[2];
    const float* Wq = (const float*)d_in[3];
    const float* bq = (const float*)d_in[4];
    const float* Wk = (const float*)d_in[5];
    const float* bk = (const float*)d_in[6];
    const float* Wv = (const float*)d_in[7];
    const float* bv = (const float*)d_in[8];
    const float* Wo = (const float*)d_in[9];
    const float* bo = (const float*)d_in[10];

    char* p = (char*)d_ws;
    f16*    Xq  = (f16*)p;    p += 33554432;   // queries f16 [32768][512]
    f16*    Xk  = (f16*)p;    p += 33554432;   // keys    f16
    f16*    Xv  = (f16*)p;    p += 33554432;   // values  f16
    f16*    QKt = (f16*)p;    p += 67108864;   // [1024][32768] f16: Q rows 0..511, K rows 512..1023
    f16*    Vb  = (f16*)p;    p += 33554432;   // V (b, l, c) f16
    f16*    agg = (f16*)p;    p += 33554432;   // aggregated V, f16
    f16*    wqh = (f16*)p;    p += 524288;     // Wq f16  (wqh+wkh = stacked Wqk, M=1024)
    f16*    wkh = (f16*)p;    p += 524288;     // Wk f16  (MUST stay adjacent to wqh)
    f16*    wvh = (f16*)p;    p += 524288;
    f16*    woh = (f16*)p;    p += 524288;
    float2* Sp  = (float2*)p; p += 8396800;    // 16 x 64 x 1025 cplx partials
    float2* Srd = (float2*)p; p += 131200;     // 16 x 1025 cplx reduced
    float*  mv  = (float*)p;  p += 131072;     // mean_value 16 x 2048
    int*    sel = (int*)p;    p += 256;        // top-7 lags
    float*  wsm = (float*)p;  p += 512;        // softmax weights 16 x 7
    f16*    Kt  = QKt + (size_t)512 * 32768;

    // conversions: 4 weights (one dispatch), 3 inputs (one dispatch)
    cvt_weights<<<dim3(256, 4), 256, 0, stream>>>(Wq, Wk, Wv, Wo, wqh, wkh, wvh, woh);
    cvt_inputs<<<dim3(16384, 3), 256, 0, stream>>>(queries, keys, values, Xq, Xk, Xv);

    // QK^T = [Wq;Wk] * X^T, X = Xq (mt<4) / Xk (mt>=4), all f16.
    // BM=128 (WM=2), BN=256 (WN=4): 8 mt x 128 nt = 1024 blocks.
    gemm_nt<1, 1, 3, 7, 1, 1><<<1024, 512, 0, stream>>>(
        wqh, Xq, Xk, QKt, 32768, bq, bk, nullptr);

    // V = Xv @ Wv^T, f16 out (b,l,c), +bv. BM=256 (WM=4), BN=128: 128x4=512 blocks.
    gemm_nt<1, 2, 7, 2, 2, 0><<<512, 512, 0, stream>>>(
        Xv, wvh, nullptr, Vb, 512, nullptr, nullptr, bv);

    // correlation spectra -> reduce -> mean_value -> selection -> aggregation
    fft_corr<<<dim3(64, 16), 256, 0, stream>>>(QKt, Kt, Sp);
    reduce_sp<<<dim3(16, 5), 256, 0, stream>>>(Sp, Srd);
    ifft_mean<<<16, 256, 0, stream>>>(Srd, mv);
    select_topk<<<1, 256, 0, stream>>>(mv, sel, wsm);
    aggregate<<<32768, 256, 0, stream>>>(Vb, sel, wsm, agg);

    // out = agg @ Wo^T + bo  -> d_out f32
    gemm_nt<0, 2, 7, 2, 2, 0><<<512, 512, 0, stream>>>(
        agg, woh, nullptr, (float*)d_out, 512, nullptr, nullptr, bo);
}

// Round 11
// 313.308 us; speedup vs baseline: 1.1133x; 1.1133x over previous
//
#include <hip/hip_runtime.h>

// AutoCorrelation attention (Autoformer) for B=16, L=2048, d=512, top_k=7.
// R1: XOR-swizzled GEMM LDS.  R2: FFT rewrite (fused radix-2, natural order).
// R3: 16x16x32 f16 MFMA + XCD tile decode.  R4: plain-f16 Q/K.  R5: merged QK
// GEMM + reduce_sp.  R6: (f32-direct staging — REVERTED.)  R7: all-f16 GEMMs.
// R8: (depth-1 dbuf — NEUTRAL.)  R9: 3-buf counted-vmcnt pipeline — NEUTRAL.
// R10: coalesced C-write epilogue (acc -> LDS tile -> linear 16B/lane stores).
//      R7-R9 invariant: dur ~= WRITE_SIZE / 665 GB/s — the 2-byte scattered
//      epilogue stores (32-B segments, 64KB row stride) were the bottleneck.

typedef _Float16 f16;
typedef _Float16 f16x8 __attribute__((ext_vector_type(8)));
typedef _Float16 f16x4 __attribute__((ext_vector_type(4)));
typedef float    f32x4 __attribute__((ext_vector_type(4)));

#define PSI(i) ((i) + ((i) >> 3))          // z anti-conflict pad (2048 -> 2304)
#define TWI(j) ((j) + ((j) >> 4))          // tw anti-conflict pad (1024 -> 1088)

__device__ __forceinline__ float2 f2add(float2 a, float2 b) { return make_float2(a.x + b.x, a.y + b.y); }
__device__ __forceinline__ float2 f2sub(float2 a, float2 b) { return make_float2(a.x - b.x, a.y - b.y); }
__device__ __forceinline__ float2 cmul(float2 a, float2 b)  { return make_float2(a.x * b.x - a.y * b.y, a.x * b.y + a.y * b.x); }

// ---------------- conversions: f32 -> f16 -----------------------------------
__global__ __launch_bounds__(256) void cvt_inputs(
    const float* __restrict__ q, const float* __restrict__ k, const float* __restrict__ v,
    f16* __restrict__ xq, f16* __restrict__ xk, f16* __restrict__ xv)
{
    const float* src = (blockIdx.y == 0) ? q : (blockIdx.y == 1) ? k : v;
    f16*         dst = (blockIdx.y == 0) ? xq : (blockIdx.y == 1) ? xk : xv;
    const int i = blockIdx.x * 256 + threadIdx.x;
    float4 val = ((const float4*)src)[i];
    f16x4 h = { (f16)val.x, (f16)val.y, (f16)val.z, (f16)val.w };
    ((f16x4*)dst)[i] = h;
}

__global__ __launch_bounds__(256) void cvt_weights(
    const float* __restrict__ w0, const float* __restrict__ w1,
    const float* __restrict__ w2, const float* __restrict__ w3,
    f16* __restrict__ o0, f16* __restrict__ o1, f16* __restrict__ o2, f16* __restrict__ o3)
{
    const float* src = (blockIdx.y == 0) ? w0 : (blockIdx.y == 1) ? w1 : (blockIdx.y == 2) ? w2 : w3;
    f16*         dst = (blockIdx.y == 0) ? o0 : (blockIdx.y == 1) ? o1 : (blockIdx.y == 2) ? o2 : o3;
    const int i = blockIdx.x * 256 + threadIdx.x;
    float4 val = ((const float4*)src)[i];
    f16x4 h = { (f16)val.x, (f16)val.y, (f16)val.z, (f16)val.w };
    ((f16x4*)dst)[i] = h;
}

// ---------------- GEMM staging: one 64-col K-slab of an NR*64-row operand ---
template<int NR>
__device__ __forceinline__ void stage_op(const f16* __restrict__ G, int row0, int k0,
                                         f16* __restrict__ lds, int tid)
{
#pragma unroll
    for (int q = 0; q < NR; ++q) {
        const int r = q * 64 + (tid >> 3);
        const int u = (tid & 7) ^ ((tid >> 3) & 7);
        const f16* g = G + (size_t)(row0 + r) * 512 + k0 + u * 8;
        f16* d = lds + q * 4096 + (tid >> 6) * 512;     // wave-uniform base
        __builtin_amdgcn_global_load_lds(
            (const __attribute__((address_space(1))) void*)g,
            (__attribute__((address_space(3))) void*)d, 16, 0, 0);
    }
}

// ---------------- NT GEMM: C[M,N] = A * B^T (+bias), f16 16x16x32 MFMA ------
// 8 waves; per-wave 64x64 output; BM = WM*64, BN = WN*64, BK = 64, K = 512.
// 3-buffer LDS, depth-2 prefetch, counted vmcnt(6) + raw s_barrier (T3+T4).
// R10: epilogue stages C tile in (dead) staging LDS, then writes 16B/lane
// fully-coalesced.
template<int F16OUT, int WM_L2, int MT_L2, int NT_L2, int SWZ, int SPLITB>
__global__ __launch_bounds__(512, 2) void gemm_nt(
    const f16* __restrict__ A0, const f16* __restrict__ B0, const f16* __restrict__ B1,
    void* __restrict__ Cout, int N,
    const float* __restrict__ bias_q, const float* __restrict__ bias_k,
    const float* __restrict__ bias_col)
{
    constexpr int WM = 1 << WM_L2;   // waves along M
    constexpr int WN = 8 >> WM_L2;   // waves along N
    constexpr int BM = WM * 64;
    constexpr int BN = WN * 64;
    constexpr int NKT = 8;           // K=512 / BK=64
    constexpr int ESZ = F16OUT ? 2 : 4;
    static_assert(BM * BN * ESZ <= 3 * (BM + BN) * 64 * 2, "C tile must fit in staging LDS");

    __shared__ __align__(16) char smem[3 * (BM + BN) * 64 * 2];
    f16* smA = (f16*)smem;                       // 3 x BM*64 f16
    f16* smB = (f16*)smem + 3 * BM * 64;         // 3 x BN*64 f16

    const int tid  = threadIdx.x;
    const int wave = tid >> 6, lane = tid & 63;

    int mt, nt;
    if (SWZ == 1) {
        const int xcd = blockIdx.x & 7, slot = blockIdx.x >> 3;
        mt = slot & ((1 << MT_L2) - 1);
        nt = (xcd << (NT_L2 - 3)) | (slot >> MT_L2);
    } else if (SWZ == 2) {
        const int xcd = blockIdx.x & 7, slot = blockIdx.x >> 3;
        nt = slot & ((1 << NT_L2) - 1);
        mt = (xcd << (MT_L2 - 3)) | (slot >> NT_L2);
    } else {
        nt = blockIdx.x & ((1 << NT_L2) - 1);
        mt = blockIdx.x >> NT_L2;
    }
    const int m0 = mt * BM, n0 = nt * BN;

    const bool useB1 = SPLITB && (mt >= (1 << (MT_L2 - 1)));
    const f16* Bg = useB1 ? B1 : B0;
    const float* brow = SPLITB
        ? (useB1 ? bias_k - (1 << (MT_L2 - 1)) * BM : bias_q)
        : bias_q;

    f32x4 acc[4][4];
#pragma unroll
    for (int m = 0; m < 4; ++m)
#pragma unroll
        for (int n = 0; n < 4; ++n) acc[m][n] = (f32x4){0.f, 0.f, 0.f, 0.f};

    const int fr = lane & 15;
    const int kg = (lane >> 4) * 8;          // k-group base within 32-wide K step
    const int rowm = fr & 7;                 // read-side swizzle key
    const int wr = wave >> (3 - WM_L2);      // wave row (0..WM-1)
    const int wc = wave & (WN - 1);          // wave col (0..WN-1)
    const int warow = wr * 64 + fr;
    const int wbrow = wc * 64 + fr;

    auto compute = [&](const f16* __restrict__ Ab, const f16* __restrict__ Bb) {
#pragma unroll
        for (int k2 = 0; k2 < 2; ++k2) {
            const int kb = k2 * 32 + kg;
            const int col = ((kb >> 3) ^ rowm) << 3;
            f16x8 af[4], bf[4];
#pragma unroll
            for (int m = 0; m < 4; ++m) af[m] = *(const f16x8*)&Ab[(warow + m * 16) * 64 + col];
#pragma unroll
            for (int n = 0; n < 4; ++n) bf[n] = *(const f16x8*)&Bb[(wbrow + n * 16) * 64 + col];
#pragma unroll
            for (int m = 0; m < 4; ++m)
#pragma unroll
                for (int n = 0; n < 4; ++n)
                    acc[m][n] = __builtin_amdgcn_mfma_f32_16x16x32_f16(af[m], bf[n], acc[m][n], 0, 0, 0);
        }
    };

    // prologue: tiles 0 and 1 in flight; wait for tile 0 only (vmcnt(6)).
    stage_op<WM>(A0, m0, 0,  smA, tid);
    stage_op<WN>(Bg, n0, 0,  smB, tid);
    stage_op<WM>(A0, m0, 64, smA + BM * 64, tid);
    stage_op<WN>(Bg, n0, 64, smB + BN * 64, tid);
    asm volatile("s_waitcnt vmcnt(6)" ::: "memory");
    __builtin_amdgcn_s_barrier();

#pragma unroll 1
    for (int kk = 0; kk < NKT; ++kk) {
        const int cur = kk % 3;
        if (kk < NKT - 2) {
            const int nxt = (kk + 2) % 3;
            stage_op<WM>(A0, m0, (kk + 2) * 64, smA + nxt * BM * 64, tid);
            stage_op<WN>(Bg, n0, (kk + 2) * 64, smB + nxt * BN * 64, tid);
        }
        compute(smA + cur * BM * 64, smB + cur * BN * 64);
        if (kk < NKT - 2) {
            // STAGE(kk+2) still in flight (6 loads) — wait only for STAGE(kk+1)
            asm volatile("s_waitcnt vmcnt(6) lgkmcnt(0)" ::: "memory");
            __builtin_amdgcn_s_barrier();
        } else if (kk == NKT - 2) {
            asm volatile("s_waitcnt vmcnt(0) lgkmcnt(0)" ::: "memory");
            __builtin_amdgcn_s_barrier();
        }
    }

    // ---- R10 coalesced epilogue: acc -> LDS C tile -> linear 16B stores ----
    __syncthreads();                       // staging LDS is now dead; reuse it
    {
        char* CT = smem;                   // BM x BN elements of ESZ bytes
        const int lr0 = wr * 64 + ((lane >> 4) << 2);
        const int lc0 = wc * 64 + fr;
#pragma unroll
        for (int m = 0; m < 4; ++m)
#pragma unroll
            for (int n = 0; n < 4; ++n) {
                const int col = lc0 + n * 16;
                const float bc = bias_col ? bias_col[n0 + col] : 0.f;
#pragma unroll
                for (int j = 0; j < 4; ++j) {
                    const int row = lr0 + m * 16 + j;
                    float v = acc[m][n][j] + bc + (brow ? brow[m0 + row] : 0.f);
                    if (F16OUT) ((f16*)CT)[row * BN + col] = (f16)v;
                    else        ((float*)CT)[row * BN + col] = v;
                }
            }
        __syncthreads();
        constexpr int CPR = BN * ESZ / 16;            // 16B chunks per row
        constexpr int CHUNKS = BM * CPR;
#pragma unroll 1
        for (int i = tid; i < CHUNKS; i += 512) {
            const int row = i / CPR;
            const int off = (i % CPR) * 16;
            int4 vv = *(const int4*)(CT + i * 16);
            *(int4*)((char*)Cout + ((size_t)(m0 + row) * N + n0) * ESZ + off) = vv;
        }
    }
}

// ---------------- 2048-pt FFT: fused double radix-2 DIF passes --------------
template<int S>
__device__ __forceinline__ void fft_pass2(float2* __restrict__ z, const float2* __restrict__ tw, int tid)
{
    constexpr int m = 1024 >> S;
    constexpr int h = m >> 1;
#pragma unroll
    for (int rep = 0; rep < 2; ++rep) {
        const int idx = tid + rep * 256;
        const int j2  = idx & (h - 1);
        const int blk = idx >> (9 - S);
        const int i   = (blk << (11 - S)) + j2;
        const float2 w1 = tw[TWI(j2 << S)];
        const float2 w2 = tw[TWI(j2 << (S + 1))];
        float2 a = z[PSI(i)], b = z[PSI(i + h)], c = z[PSI(i + m)], d = z[PSI(i + m + h)];
        float2 a1 = f2add(a, c);
        float2 c1 = cmul(f2sub(a, c), w1);
        float2 b1 = f2add(b, d);
        float2 t0 = cmul(f2sub(b, d), w1);
        float2 d1 = make_float2(t0.y, -t0.x);            // * (-i)  (w_{j+h} = -i*w_j)
        z[PSI(i)]         = f2add(a1, b1);
        z[PSI(i + h)]     = cmul(f2sub(a1, b1), w2);
        z[PSI(i + m)]     = f2add(c1, d1);
        z[PSI(i + m + h)] = cmul(f2sub(c1, d1), w2);
    }
    __syncthreads();
}

__device__ __forceinline__ void fft_tail_scatter(float2* __restrict__ z, int tid)
{
    float2 v[8];
    const int p0 = tid * 8;
#pragma unroll
    for (int e = 0; e < 8; ++e) v[e] = z[PSI(p0 + e)];
    __syncthreads();
    constexpr float RS = 0.70710678118654752f;
    const float2 W8[4] = { {1.f, 0.f}, {RS, -RS}, {0.f, -1.f}, {-RS, -RS} };
#pragma unroll
    for (int e = 0; e < 4; ++e) {
        float2 t = f2sub(v[e], v[e + 4]);
        v[e]     = f2add(v[e], v[e + 4]);
        v[e + 4] = cmul(t, W8[e]);
    }
#pragma unroll
    for (int base = 0; base < 8; base += 4) {
        float2 t0 = f2sub(v[base], v[base + 2]);
        v[base]     = f2add(v[base], v[base + 2]);
        v[base + 2] = t0;
        float2 t1 = f2sub(v[base + 1], v[base + 3]);
        v[base + 1] = f2add(v[base + 1], v[base + 3]);
        v[base + 3] = make_float2(t1.y, -t1.x);
    }
#pragma unroll
    for (int base = 0; base < 8; base += 2) {
        float2 t = f2sub(v[base], v[base + 1]);
        v[base]     = f2add(v[base], v[base + 1]);
        v[base + 1] = t;
    }
    const int br8t = (int)(__brev((unsigned)tid) >> 24);
    const int BR3[8] = {0, 4, 2, 6, 1, 5, 3, 7};
#pragma unroll
    for (int e = 0; e < 8; ++e) {
        const int f = br8t + (BR3[e] << 8);
        z[PSI(f)] = v[e];
    }
    __syncthreads();
}

__device__ __forceinline__ void fft2048_natural(float2* __restrict__ z, const float2* __restrict__ tw, int tid)
{
    fft_pass2<0>(z, tw, tid);
    fft_pass2<2>(z, tw, tid);
    fft_pass2<4>(z, tw, tid);
    fft_pass2<6>(z, tw, tid);
    fft_tail_scatter(z, tid);   // z now holds Z[f] at natural f (PSI-mapped)
}

__device__ __forceinline__ void fill_tw(float2* __restrict__ tw, int tid)
{
    for (int j = tid; j < 1024; j += 256) {
        float sv, cv;
        sincospif(-(float)j * (1.0f / 1024.0f), &sv, &cv);   // e^{-2 pi i j / 2048}
        tw[TWI(j)] = make_float2(cv, sv);
    }
}

// 8 channels/block: z = q + i*k packed FFT; S_c = Q*conj(K) accumulated in
// registers over channels; Hermitian half f=0..1024 written to Sp.
__global__ __launch_bounds__(256) void fft_corr(
    const f16* __restrict__ Qt, const f16* __restrict__ Kt,
    float2* __restrict__ Sp)
{
    __shared__ float2 z[2304];
    __shared__ float2 tw[1088];
    const int tid = threadIdx.x;
    const int grp = blockIdx.x;   // 0..63 channel group (8 ch each)
    const int b   = blockIdx.y;   // 0..15 batch

    fill_tw(tw, tid);
    float2 racc[5];
#pragma unroll
    for (int r = 0; r < 5; ++r) racc[r] = make_float2(0.f, 0.f);
    __syncthreads();

    for (int ch = 0; ch < 8; ++ch) {
        const int c = grp * 8 + ch;
        const f16x8* qr = (const f16x8*)(Qt + ((size_t)c * 16 + b) * 2048);
        const f16x8* kr = (const f16x8*)(Kt + ((size_t)c * 16 + b) * 2048);
        f16x8 qv = qr[tid], kv = kr[tid];
        const int e0 = tid * 8;
#pragma unroll
        for (int j = 0; j < 8; ++j)
            z[PSI(e0 + j)] = make_float2((float)qv[j], (float)kv[j]);
        __syncthreads();
        fft2048_natural(z, tw, tid);
#pragma unroll
        for (int r = 0; r < 5; ++r) {
            const int f = tid + (r << 8);
            if (f <= 1024) {
                const int pf = (2048 - f) & 2047;
                float2 Zf  = z[PSI(f)];
                float2 Zc0 = z[PSI(pf)];
                float qx = 0.5f * (Zf.x + Zc0.x), qy = 0.5f * (Zf.y - Zc0.y);
                float dx = Zf.x - Zc0.x,          dy = Zf.y + Zc0.y;
                float kx = 0.5f * dy,             ky = -0.5f * dx;   // K = -i*D/2
                racc[r].x += qx * kx + qy * ky;                      // Q*conj(K)
                racc[r].y += qy * kx - qx * ky;
            }
        }
        __syncthreads();
    }
    float2* out = Sp + ((size_t)b * 64 + grp) * 1025;
#pragma unroll
    for (int r = 0; r < 5; ++r) {
        const int f = tid + (r << 8);
        if (f <= 1024) out[f] = racc[r];
    }
}

// fixed-order sum of the 64 per-group spectra -> Sred[b][f]
__global__ __launch_bounds__(256) void reduce_sp(
    const float2* __restrict__ Sp, float2* __restrict__ Sred)
{
    const int b = blockIdx.x;
    const int f = blockIdx.y * 256 + threadIdx.x;
    if (f > 1024) return;
    const float2* base = Sp + (size_t)b * 64 * 1025 + f;
    float sx = 0.f, sy = 0.f;
#pragma unroll 8
    for (int g = 0; g < 64; ++g) {
        float2 p = base[(size_t)g * 1025];
        sx += p.x; sy += p.y;
    }
    Sred[b * 1025 + f] = make_float2(sx, sy);
}

// rebuild full spectrum from Hermitian half, inverse FFT via conj trick
// (same natural-order forward FFT), write mean_value.
__global__ __launch_bounds__(256) void ifft_mean(
    const float2* __restrict__ Sred, float* __restrict__ mv)
{
    __shared__ float2 z[2304];
    __shared__ float2 tw[1088];
    const int tid = threadIdx.x;
    const int b   = blockIdx.x;
    fill_tw(tw, tid);
#pragma unroll
    for (int r = 0; r < 5; ++r) {
        const int f = tid + (r << 8);
        if (f <= 1024) {
            float2 s = Sred[b * 1025 + f];
            z[PSI(f)] = make_float2(s.x, -s.y);                     // conj(S[f])
            if (f >= 1 && f <= 1023)
                z[PSI(2048 - f)] = make_float2(s.x, s.y);           // conj(S[2048-f]) = S[f]
        }
    }
    __syncthreads();
    fft2048_natural(z, tw, tid);
    const float scale = 1.0f / (2048.0f * 512.0f);  // irfft 1/N and channel mean
    for (int t = tid; t < 2048; t += 256)
        mv[(size_t)b * 2048 + t] = z[PSI(t)].x * scale;
}

// top-7 lags of batch-mean corr + per-batch softmax weights. One block.
__global__ __launch_bounds__(256) void select_topk(
    const float* __restrict__ mv, int* __restrict__ sel, float* __restrict__ wsm)
{
    __shared__ float u[2048];
    __shared__ float rv[256];
    __shared__ int   ri[256];
    __shared__ int   ssel[7];
    const int tid = threadIdx.x;
    for (int t = tid; t < 2048; t += 256) {
        float s = 0.f;
        for (int b = 0; b < 16; ++b) s += mv[b * 2048 + t];
        u[t] = s;
    }
    __syncthreads();
    for (int k = 0; k < 7; ++k) {
        float best = -3.4e38f; int bi = 0x7fffffff;
        for (int t = tid; t < 2048; t += 256)
            if (u[t] > best) { best = u[t]; bi = t; }
        rv[tid] = best; ri[tid] = bi;
        __syncthreads();
        for (int off = 128; off > 0; off >>= 1) {
            if (tid < off) {
                if (rv[tid + off] > rv[tid] ||
                    (rv[tid + off] == rv[tid] && ri[tid + off] < ri[tid])) {
                    rv[tid] = rv[tid + off]; ri[tid] = ri[tid + off];
                }
            }
            __syncthreads();
        }
        if (tid == 0) { ssel[k] = ri[0]; sel[k] = ri[0]; u[ri[0]] = -3.4e38f; }
        __syncthreads();
    }
    if (tid < 16) {
        float vals[7], mx = -3.4e38f;
        for (int k = 0; k < 7; ++k) { vals[k] = mv[tid * 2048 + ssel[k]]; mx = fmaxf(mx, vals[k]); }
        float se = 0.f;
        for (int k = 0; k < 7; ++k) { vals[k] = expf(vals[k] - mx); se += vals[k]; }
        for (int k = 0; k < 7; ++k) wsm[tid * 7 + k] = vals[k] / se;
    }
}

// agg[b,l,c] = sum_k w[b,k] * V[b,(l+sel[k])%L,c]
__global__ __launch_bounds__(256) void aggregate(
    const f16* __restrict__ V, const int* __restrict__ sel,
    const float* __restrict__ wsm, f16* __restrict__ agg)
{
    __shared__ int   sidx[7];
    __shared__ float sw[7];
    const int bl = blockIdx.x;
    const int b = bl >> 11, l = bl & 2047;
    if (threadIdx.x < 7) { sidx[threadIdx.x] = sel[threadIdx.x]; sw[threadIdx.x] = wsm[b * 7 + threadIdx.x]; }
    __syncthreads();
    const int c = threadIdx.x;
    float a0 = 0.f, a1 = 0.f;
#pragma unroll
    for (int k = 0; k < 7; ++k) {
        const int lk = (l + sidx[k]) & 2047;
        const f16* row = V + ((size_t)b * 2048 + lk) * 512;
        a0 += sw[k] * (float)row[c];
        a1 += sw[k] * (float)row[c + 256];
    }
    f16* orow = agg + ((size_t)b * 2048 + l) * 512;
    orow[c]       = (f16)a0;
    orow[c + 256] = (f16)a1;
}

extern "C" void kernel_launch(void* const* d_in, const int* in_sizes, int n_in,
                              void* d_out, int out_size, void* d_ws, size_t ws_size,
                              hipStream_t stream)
{
    (void)in_sizes; (void)n_in; (void)out_size; (void)ws_size;
    const float* queries = (const float*)d_in[0];
    const float* keys    = (const float*)d_in[1];
    const float* values  = (const float*)d_in[2];
    const float* Wq = (const float*)d_in[3];
    const float* bq = (const float*)d_in[4];
    const float* Wk = (const float*)d_in[5];
    const float* bk = (const float*)d_in[6];
    const float* Wv = (const float*)d_in[7];
    const float* bv = (const float*)d_in[8];
    const float* Wo = (const float*)d_in[9];
    const float* bo = (const float*)d_in[10];

    char* p = (char*)d_ws;
    f16*    Xq  = (f16*)p;    p += 33554432;   // queries f16 [32768][512]
    f16*    Xk  = (f16*)p;    p += 33554432;   // keys    f16
    f16*    Xv  = (f16*)p;    p += 33554432;   // values  f16
    f16*    QKt = (f16*)p;    p += 67108864;   // [1024][32768] f16: Q rows 0..511, K rows 512..1023
    f16*    Vb  = (f16*)p;    p += 33554432;   // V (b, l, c) f16
    f16*    agg = (f16*)p;    p += 33554432;   // aggregated V, f16
    f16*    wqh = (f16*)p;    p += 524288;     // Wq f16  (wqh+wkh = stacked Wqk, M=1024)
    f16*    wkh = (f16*)p;    p += 524288;     // Wk f16  (MUST stay adjacent to wqh)
    f16*    wvh = (f16*)p;    p += 524288;
    f16*    woh = (f16*)p;    p += 524288;
    float2* Sp  = (float2*)p; p += 8396800;    // 16 x 64 x 1025 cplx partials
    float2* Srd = (float2*)p; p += 131200;     // 16 x 1025 cplx reduced
    float*  mv  = (float*)p;  p += 131072;     // mean_value 16 x 2048
    int*    sel = (int*)p;    p += 256;        // top-7 lags
    float*  wsm = (float*)p;  p += 512;        // softmax weights 16 x 7
    f16*    Kt  = QKt + (size_t)512 * 32768;

    // conversions: 4 weights (one dispatch), 3 inputs (one dispatch)
    cvt_weights<<<dim3(256, 4), 256, 0, stream>>>(Wq, Wk, Wv, Wo, wqh, wkh, wvh, woh);
    cvt_inputs<<<dim3(16384, 3), 256, 0, stream>>>(queries, keys, values, Xq, Xk, Xv);

    // QK^T = [Wq;Wk] * X^T, X = Xq (mt<4) / Xk (mt>=4), all f16.
    // BM=128 (WM=2), BN=256 (WN=4): 8 mt x 128 nt = 1024 blocks.
    gemm_nt<1, 1, 3, 7, 1, 1><<<1024, 512, 0, stream>>>(
        wqh, Xq, Xk, QKt, 32768, bq, bk, nullptr);

    // V = Xv @ Wv^T, f16 out (b,l,c), +bv. BM=256 (WM=4), BN=128: 128x4=512 blocks.
    gemm_nt<1, 2, 7, 2, 2, 0><<<512, 512, 0, stream>>>(
        Xv, wvh, nullptr, Vb, 512, nullptr, nullptr, bv);

    // correlation spectra -> reduce -> mean_value -> selection -> aggregation
    fft_corr<<<dim3(64, 16), 256, 0, stream>>>(QKt, Kt, Sp);
    reduce_sp<<<dim3(16, 5), 256, 0, stream>>>(Sp, Srd);
    ifft_mean<<<16, 256, 0, stream>>>(Srd, mv);
    select_topk<<<1, 256, 0, stream>>>(mv, sel, wsm);
    aggregate<<<32768, 256, 0, stream>>>(Vb, sel, wsm, agg);

    // out = agg @ Wo^T + bo  -> d_out f32
    gemm_nt<0, 2, 7, 2, 2, 0><<<512, 512, 0, stream>>>(
        agg, woh, nullptr, (float*)d_out, 512, nullptr, nullptr, bo);
}